// Round 1
// baseline (1394.263 us; speedup 1.0000x reference)
//
#include <hip/hip_runtime.h>
#include <hip/hip_cooperative_groups.h>
#include <math.h>

namespace cg = cooperative_groups;

// Problem constants
#define PSTR 40     // LDS fp16 patch row stride: 80 B (16B-aligned, uniform banks)

typedef _Float16 half8 __attribute__((ext_vector_type(8)));
typedef float    f32x4 __attribute__((ext_vector_type(4)));

__device__ __forceinline__ float fast_tanh(float v) {
    float e = __expf(2.f * v);
    return 1.f - 2.f / (e + 1.f);
}
__device__ __forceinline__ float hsig(float v) {
    return fminf(fmaxf(0.2f * v + 0.5f, 0.f), 1.f);
}

// Pack weights: Wcx[tap][n][ci<32] from Wx[tap][ci][n]; Wch[tap][n][ci] from Wh[tap][ci][n]
__global__ void prep_w(const float* __restrict__ Wx, const float* __restrict__ Wh,
                       _Float16* __restrict__ Wcx, _Float16* __restrict__ Wch) {
    const int k = blockIdx.x;      // 0..575 = tap*64 + ci
    const int n = threadIdx.x;     // 0..127
    const int tap = k >> 6, ci = k & 63;
    if (ci < 32) Wcx[(tap * 128 + n) * 32 + ci]        = (_Float16)Wx[(tap * 32 + ci) * 128 + n];
    else         Wch[(tap * 128 + n) * 32 + (ci - 32)] = (_Float16)Wh[(tap * 32 + (ci - 32)) * 128 + n];
}

// One fused timestep: stage x patch (+h patch if t>0), x-conv + h-conv MFMA into
// bias-initialized accumulators, LSTM gate math with c in registers, write h + BN out.
// Wave (chg=w&1, mtg=w>>1): 32 px x 64 ch. acc[mt][nt]: px=(mtg*2+mt)*16+quad*4+r,
// ch = nt*32 + chg*16 + l15  (nt = gate, f = chg*16+l15).
__device__ __forceinline__ void lstm_step(
    const float* __restrict__ x, const _Float16* __restrict__ Wcx,
    const _Float16* __restrict__ Wch,
    const float* bi, float inv, float bnb,
    int t, int b, int px0, int py0,
    int tid, int l15, int quad, int chg, int mtg,
    const _Float16* __restrict__ hprev, _Float16* __restrict__ hnext,
    float* __restrict__ out, f32x4& c0, f32x4& c1,
    _Float16* xp, _Float16* hp)
{
    // stage x patch (fp32 -> fp16)
    const float* xt = x + (((size_t)b * 16 + t) * 4096) * 32;
    for (int i = tid; i < 400; i += 256) {
        const int pos = i >> 2, q = i & 3;
        const int row = pos / 10, col = pos - row * 10;
        const int gy = py0 + row - 1, gx = px0 + col - 1;
        half8 hv = {0, 0, 0, 0, 0, 0, 0, 0};
        if ((unsigned)gy < 64u && (unsigned)gx < 64u) {
            const float* s = xt + ((size_t)(gy * 64 + gx)) * 32 + q * 8;
            const float4 v0 = *(const float4*)s;
            const float4 v1 = *(const float4*)(s + 4);
            hv = (half8){(_Float16)v0.x, (_Float16)v0.y, (_Float16)v0.z, (_Float16)v0.w,
                         (_Float16)v1.x, (_Float16)v1.y, (_Float16)v1.z, (_Float16)v1.w};
        }
        *(half8*)&xp[pos * PSTR + q * 8] = hv;
    }
    if (t > 0) {
        const _Float16* hb = hprev + (size_t)b * 4096 * 32;
        for (int i = tid; i < 400; i += 256) {
            const int pos = i >> 2, q = i & 3;
            const int row = pos / 10, col = pos - row * 10;
            const int gy = py0 + row - 1, gx = px0 + col - 1;
            half8 hv = {0, 0, 0, 0, 0, 0, 0, 0};
            if ((unsigned)gy < 64u && (unsigned)gx < 64u)
                hv = *(const half8*)(hb + ((size_t)(gy * 64 + gx)) * 32 + q * 8);
            *(half8*)&hp[pos * PSTR + q * 8] = hv;
        }
    }
    __syncthreads();

    f32x4 acc[2][4];
    #pragma unroll
    for (int mt = 0; mt < 2; ++mt)
        #pragma unroll
        for (int nt = 0; nt < 4; ++nt)
            acc[mt][nt] = (f32x4){bi[nt], bi[nt], bi[nt], bi[nt]};

    const int pbase = ((mtg * 4 + (l15 >> 3)) * 10 + (l15 & 7)) * PSTR + quad * 8;
    const _Float16* wbx = Wcx + (chg * 16 + l15) * 32 + quad * 8;

    #pragma unroll
    for (int tap = 0; tap < 9; ++tap) {
        const int ky = tap / 3, kx = tap - ky * 3;
        const half8 a0 = *(const half8*)&xp[pbase + (ky * 10 + kx) * PSTR];
        const half8 a1 = *(const half8*)&xp[pbase + (ky * 10 + kx + 20) * PSTR];
        #pragma unroll
        for (int nt = 0; nt < 4; ++nt) {
            const half8 bf = *(const half8*)(wbx + tap * 4096 + nt * 1024);
            acc[0][nt] = __builtin_amdgcn_mfma_f32_16x16x32_f16(a0, bf, acc[0][nt], 0, 0, 0);
            acc[1][nt] = __builtin_amdgcn_mfma_f32_16x16x32_f16(a1, bf, acc[1][nt], 0, 0, 0);
        }
    }
    if (t > 0) {
        const _Float16* wbh = Wch + (chg * 16 + l15) * 32 + quad * 8;
        #pragma unroll
        for (int tap = 0; tap < 9; ++tap) {
            const int ky = tap / 3, kx = tap - ky * 3;
            const half8 a0 = *(const half8*)&hp[pbase + (ky * 10 + kx) * PSTR];
            const half8 a1 = *(const half8*)&hp[pbase + (ky * 10 + kx + 20) * PSTR];
            #pragma unroll
            for (int nt = 0; nt < 4; ++nt) {
                const half8 bf = *(const half8*)(wbh + tap * 4096 + nt * 1024);
                acc[0][nt] = __builtin_amdgcn_mfma_f32_16x16x32_f16(a0, bf, acc[0][nt], 0, 0, 0);
                acc[1][nt] = __builtin_amdgcn_mfma_f32_16x16x32_f16(a1, bf, acc[1][nt], 0, 0, 0);
            }
        }
    }

    // epilogue: LSTM gate math (c in registers), write h + BN out
    _Float16* hq = hnext + (size_t)b * 4096 * 32;
    float* oq = out + (((size_t)b * 16 + t) * 4096) * 32;
    const int f = chg * 16 + l15;
    f32x4 cn0, cn1;
    #pragma unroll
    for (int mt = 0; mt < 2; ++mt) {
        #pragma unroll
        for (int r = 0; r < 4; ++r) {
            const int px = (mtg * 2 + mt) * 16 + quad * 4 + r;
            const int gy = py0 + (px >> 3), gx = px0 + (px & 7);
            const float gi = acc[mt][0][r];
            const float gf = acc[mt][1][r];
            const float gc = acc[mt][2][r];
            const float go = acc[mt][3][r];
            const float co = mt ? c1[r] : c0[r];
            const float cn = hsig(gf) * co + hsig(gi) * fast_tanh(gc);
            const float hv = hsig(go) * fast_tanh(cn);
            if (mt) cn1[r] = cn; else cn0[r] = cn;
            const size_t pix = ((size_t)(gy * 64 + gx)) * 32 + f;
            hq[pix] = (_Float16)hv;
            oq[pix] = hv * inv + bnb;
        }
    }
    c0 = cn0; c1 = cn1;
}

// Persistent cooperative kernel: whole time loop on-device; c lives in registers.
// Grid (8,8,8): blockIdx.x = batch (round-robin -> one XCD per image), .y/.z = tile.
// 512 blocks x 4 waves = 2 blocks/CU co-resident.
__global__ __launch_bounds__(256, 2)
void convlstm_fused(const float* __restrict__ x, const _Float16* __restrict__ Wcx,
                    const _Float16* __restrict__ Wch, const float* __restrict__ bias,
                    const float* __restrict__ gamma_, const float* __restrict__ beta_,
                    const float* __restrict__ mmean, const float* __restrict__ mvar,
                    _Float16* __restrict__ h0, _Float16* __restrict__ h1,
                    float* __restrict__ out)
{
    __shared__ _Float16 xp[100 * PSTR];   // 8 KB: 10x10 halo x 32 x-ch
    __shared__ _Float16 hp[100 * PSTR];   // 8 KB: 10x10 halo x 32 h-ch
    cg::grid_group grid = cg::this_grid();

    const int tid  = threadIdx.x;
    const int lane = tid & 63;
    const int w    = tid >> 6;
    const int l15  = lane & 15, quad = lane >> 4;
    const int chg  = w & 1, mtg = w >> 1;
    const int b = blockIdx.x, tx = blockIdx.y, ty = blockIdx.z;
    const int px0 = tx * 8, py0 = ty * 8;

    const int f = chg * 16 + l15;
    float bi[4];
    #pragma unroll
    for (int nt = 0; nt < 4; ++nt) bi[nt] = bias[nt * 32 + f];
    const float inv = gamma_[f] * rsqrtf(mvar[f] + 1e-3f);
    const float bnb = beta_[f] - mmean[f] * inv;

    f32x4 c0 = (f32x4){0.f, 0.f, 0.f, 0.f};
    f32x4 c1 = (f32x4){0.f, 0.f, 0.f, 0.f};
    _Float16* hprev = h0;
    _Float16* hnext = h1;
    for (int t = 0; t < 16; ++t) {
        lstm_step(x, Wcx, Wch, bi, inv, bnb, t, b, px0, py0,
                  tid, l15, quad, chg, mtg, hprev, hnext, out, c0, c1, xp, hp);
        if (t < 15) grid.sync();   // h halo exchange barrier (double-buffered h)
        _Float16* tmp = hprev; hprev = hnext; hnext = tmp;
    }
}

// Fallback (if cooperative launch is refused): one fused step per launch, c in global.
__global__ __launch_bounds__(256, 2)
void lstm_step_k(const float* __restrict__ x, const _Float16* __restrict__ Wcx,
                 const _Float16* __restrict__ Wch, const float* __restrict__ bias,
                 const float* __restrict__ gamma_, const float* __restrict__ beta_,
                 const float* __restrict__ mmean, const float* __restrict__ mvar,
                 const _Float16* __restrict__ hprev, _Float16* __restrict__ hnext,
                 float* __restrict__ csw, float* __restrict__ out, int t)
{
    __shared__ _Float16 xp[100 * PSTR];
    __shared__ _Float16 hp[100 * PSTR];

    const int tid  = threadIdx.x;
    const int lane = tid & 63;
    const int w    = tid >> 6;
    const int l15  = lane & 15, quad = lane >> 4;
    const int chg  = w & 1, mtg = w >> 1;
    const int b = blockIdx.x, tx = blockIdx.y, ty = blockIdx.z;
    const int px0 = tx * 8, py0 = ty * 8;
    const int tile = ty * 8 + tx;

    const int f = chg * 16 + l15;
    float bi[4];
    #pragma unroll
    for (int nt = 0; nt < 4; ++nt) bi[nt] = bias[nt * 32 + f];
    const float inv = gamma_[f] * rsqrtf(mvar[f] + 1e-3f);
    const float bnb = beta_[f] - mmean[f] * inv;

    float* cp = csw + (((size_t)b * 64 + tile) * 256 + tid) * 8;
    f32x4 c0 = *(const f32x4*)cp;
    f32x4 c1 = *(const f32x4*)(cp + 4);

    lstm_step(x, Wcx, Wch, bi, inv, bnb, t, b, px0, py0,
              tid, l15, quad, chg, mtg, hprev, hnext, out, c0, c1, xp, hp);

    *(f32x4*)cp       = c0;
    *(f32x4*)(cp + 4) = c1;
}

extern "C" void kernel_launch(void* const* d_in, const int* in_sizes, int n_in,
                              void* d_out, int out_size, void* d_ws, size_t ws_size,
                              hipStream_t stream)
{
    const float* x      = (const float*)d_in[0];
    const float* Wx     = (const float*)d_in[1];
    const float* Wh     = (const float*)d_in[2];
    const float* bias   = (const float*)d_in[3];
    const float* gamma_ = (const float*)d_in[4];
    const float* beta_  = (const float*)d_in[5];
    const float* mmean  = (const float*)d_in[6];
    const float* mvar   = (const float*)d_in[7];
    float* out = (float*)d_out;

    // ws: [h0 2MB][h1 2MB][csw 4MB][Wcx 72KB][Wch 72KB]
    char* wsb = (char*)d_ws;
    _Float16* h0  = (_Float16*)(wsb);
    _Float16* h1  = (_Float16*)(wsb + (1 << 21));
    float*    csw = (float*)(wsb + (1 << 22));
    _Float16* Wcx = (_Float16*)(wsb + (1 << 23));
    _Float16* Wch = (_Float16*)(wsb + (1 << 23) + 73728);

    prep_w<<<dim3(576), dim3(128), 0, stream>>>(Wx, Wh, Wcx, Wch);

    // Persistent fused kernel: no memset needed (t=0 skips h-conv; c starts in regs).
    void* args[] = {(void*)&x, (void*)&Wcx, (void*)&Wch, (void*)&bias,
                    (void*)&gamma_, (void*)&beta_, (void*)&mmean, (void*)&mvar,
                    (void*)&h0, (void*)&h1, (void*)&out};
    hipError_t e = hipLaunchCooperativeKernel((void*)convlstm_fused, dim3(8, 8, 8),
                                              dim3(256), args, 0, stream);
    if (e != hipSuccess) {
        // Fallback: 16 sequential fused-step launches, c round-trips via csw.
        hipMemsetAsync(csw, 0, 1 << 22, stream);
        _Float16* hpr = h0;
        _Float16* hnx = h1;
        for (int t = 0; t < 16; ++t) {
            lstm_step_k<<<dim3(8, 8, 8), 256, 0, stream>>>(
                x, Wcx, Wch, bias, gamma_, beta_, mmean, mvar, hpr, hnx, csw, out, t);
            _Float16* tmp = hpr; hpr = hnx; hnx = tmp;
        }
    }
}

// Round 2
// 346.705 us; speedup vs baseline: 4.0215x; 4.0215x over previous
//
#include <hip/hip_runtime.h>
#include <math.h>

// Problem constants
#define PSTR 40     // LDS fp16 patch row stride: 80 B (16B-aligned, uniform banks)

typedef _Float16 half8 __attribute__((ext_vector_type(8)));
typedef float    f32x4 __attribute__((ext_vector_type(4)));

__device__ __forceinline__ float fast_tanh(float v) {
    float e = __expf(2.f * v);
    return 1.f - 2.f / (e + 1.f);
}
__device__ __forceinline__ float hsig(float v) {
    return fminf(fmaxf(0.2f * v + 0.5f, 0.f), 1.f);
}

// Pack weights: Wcx[tap][n][ci<32] from Wx[tap][ci][n]; Wch[tap][n][ci] from Wh[tap][ci][n]
__global__ void prep_w(const float* __restrict__ Wx, const float* __restrict__ Wh,
                       _Float16* __restrict__ Wcx, _Float16* __restrict__ Wch) {
    const int k = blockIdx.x;      // 0..575 = tap*64 + ci
    const int n = threadIdx.x;     // 0..127
    const int tap = k >> 6, ci = k & 63;
    if (ci < 32) Wcx[(tap * 128 + n) * 32 + ci]        = (_Float16)Wx[(tap * 32 + ci) * 128 + n];
    else         Wch[(tap * 128 + n) * 32 + (ci - 32)] = (_Float16)Wh[(tap * 32 + (ci - 32)) * 128 + n];
}

// One fused timestep per launch: stage x patch (+h patch if t>0), x-conv + h-conv MFMA
// into bias-initialized accumulators, LSTM gate math, write h (fp16) + BN out (fp32).
// c round-trips through csw (fp32) except t==0 where c starts as 0 in registers.
// Wave (chg=w&1, mtg=w>>1): 32 px x 64 ch. acc[mt][nt]: px=(mtg*2+mt)*16+quad*4+r,
// ch = nt*32 + chg*16 + l15  (nt = gate, f = chg*16+l15).
// Grid (8,8,8): blockIdx.x = batch -> round-robin puts all 64 tiles of a batch on one
// XCD (halo reads of hprev are L2-local); launch boundary provides coherence.
__global__ __launch_bounds__(256, 2)
void lstm_step_k(const float* __restrict__ x, const _Float16* __restrict__ Wcx,
                 const _Float16* __restrict__ Wch, const float* __restrict__ bias,
                 const float* __restrict__ gamma_, const float* __restrict__ beta_,
                 const float* __restrict__ mmean, const float* __restrict__ mvar,
                 const _Float16* __restrict__ hprev, _Float16* __restrict__ hnext,
                 float* __restrict__ csw, float* __restrict__ out, int t)
{
    __shared__ _Float16 xp[100 * PSTR];   // 8 KB: 10x10 halo x 32 x-ch
    __shared__ _Float16 hp[100 * PSTR];   // 8 KB: 10x10 halo x 32 h-ch

    const int tid  = threadIdx.x;
    const int lane = tid & 63;
    const int w    = tid >> 6;
    const int l15  = lane & 15, quad = lane >> 4;
    const int chg  = w & 1, mtg = w >> 1;
    const int b = blockIdx.x, tx = blockIdx.y, ty = blockIdx.z;
    const int px0 = tx * 8, py0 = ty * 8;
    const int tile = ty * 8 + tx;

    // ---- stage x patch (fp32 -> fp16) and h patch (fp16) ----
    const float* xt = x + (((size_t)b * 16 + t) * 4096) * 32;
    for (int i = tid; i < 400; i += 256) {
        const int pos = i >> 2, q = i & 3;
        const int row = pos / 10, col = pos - row * 10;
        const int gy = py0 + row - 1, gx = px0 + col - 1;
        half8 hv = {0, 0, 0, 0, 0, 0, 0, 0};
        if ((unsigned)gy < 64u && (unsigned)gx < 64u) {
            const float* s = xt + ((size_t)(gy * 64 + gx)) * 32 + q * 8;
            const float4 v0 = *(const float4*)s;
            const float4 v1 = *(const float4*)(s + 4);
            hv = (half8){(_Float16)v0.x, (_Float16)v0.y, (_Float16)v0.z, (_Float16)v0.w,
                         (_Float16)v1.x, (_Float16)v1.y, (_Float16)v1.z, (_Float16)v1.w};
        }
        *(half8*)&xp[pos * PSTR + q * 8] = hv;
    }
    if (t > 0) {
        const _Float16* hb = hprev + (size_t)b * 4096 * 32;
        for (int i = tid; i < 400; i += 256) {
            const int pos = i >> 2, q = i & 3;
            const int row = pos / 10, col = pos - row * 10;
            const int gy = py0 + row - 1, gx = px0 + col - 1;
            half8 hv = {0, 0, 0, 0, 0, 0, 0, 0};
            if ((unsigned)gy < 64u && (unsigned)gx < 64u)
                hv = *(const half8*)(hb + ((size_t)(gy * 64 + gx)) * 32 + q * 8);
            *(half8*)&hp[pos * PSTR + q * 8] = hv;
        }
    }
    __syncthreads();

    // ---- gate bias + BN constants ----
    const int f = chg * 16 + l15;
    float bi[4];
    #pragma unroll
    for (int nt = 0; nt < 4; ++nt) bi[nt] = bias[nt * 32 + f];
    const float inv = gamma_[f] * rsqrtf(mvar[f] + 1e-3f);
    const float bnb = beta_[f] - mmean[f] * inv;

    f32x4 acc[2][4];
    #pragma unroll
    for (int mt = 0; mt < 2; ++mt)
        #pragma unroll
        for (int nt = 0; nt < 4; ++nt)
            acc[mt][nt] = (f32x4){bi[nt], bi[nt], bi[nt], bi[nt]};

    const int pbase = ((mtg * 4 + (l15 >> 3)) * 10 + (l15 & 7)) * PSTR + quad * 8;
    const _Float16* wbx = Wcx + (chg * 16 + l15) * 32 + quad * 8;

    // ---- x-conv: 9 taps x 4 gates x 2 px-halves ----
    #pragma unroll
    for (int tap = 0; tap < 9; ++tap) {
        const int ky = tap / 3, kx = tap - ky * 3;
        const half8 a0 = *(const half8*)&xp[pbase + (ky * 10 + kx) * PSTR];
        const half8 a1 = *(const half8*)&xp[pbase + (ky * 10 + kx + 20) * PSTR];
        #pragma unroll
        for (int nt = 0; nt < 4; ++nt) {
            const half8 bf = *(const half8*)(wbx + tap * 4096 + nt * 1024);
            acc[0][nt] = __builtin_amdgcn_mfma_f32_16x16x32_f16(a0, bf, acc[0][nt], 0, 0, 0);
            acc[1][nt] = __builtin_amdgcn_mfma_f32_16x16x32_f16(a1, bf, acc[1][nt], 0, 0, 0);
        }
    }
    // ---- h-conv (skipped at t=0: h0 == 0) ----
    if (t > 0) {
        const _Float16* wbh = Wch + (chg * 16 + l15) * 32 + quad * 8;
        #pragma unroll
        for (int tap = 0; tap < 9; ++tap) {
            const int ky = tap / 3, kx = tap - ky * 3;
            const half8 a0 = *(const half8*)&hp[pbase + (ky * 10 + kx) * PSTR];
            const half8 a1 = *(const half8*)&hp[pbase + (ky * 10 + kx + 20) * PSTR];
            #pragma unroll
            for (int nt = 0; nt < 4; ++nt) {
                const half8 bf = *(const half8*)(wbh + tap * 4096 + nt * 1024);
                acc[0][nt] = __builtin_amdgcn_mfma_f32_16x16x32_f16(a0, bf, acc[0][nt], 0, 0, 0);
                acc[1][nt] = __builtin_amdgcn_mfma_f32_16x16x32_f16(a1, bf, acc[1][nt], 0, 0, 0);
            }
        }
    }

    // ---- cell state: registers at t=0, else load from csw ----
    float* cp = csw + (((size_t)b * 64 + tile) * 256 + tid) * 8;
    f32x4 c0 = (f32x4){0.f, 0.f, 0.f, 0.f};
    f32x4 c1 = (f32x4){0.f, 0.f, 0.f, 0.f};
    if (t > 0) {
        c0 = *(const f32x4*)cp;
        c1 = *(const f32x4*)(cp + 4);
    }

    // ---- LSTM gate math + BN + writes ----
    _Float16* hq = hnext + (size_t)b * 4096 * 32;
    float* oq = out + (((size_t)b * 16 + t) * 4096) * 32;
    f32x4 cn0, cn1;
    #pragma unroll
    for (int mt = 0; mt < 2; ++mt) {
        #pragma unroll
        for (int r = 0; r < 4; ++r) {
            const int px = (mtg * 2 + mt) * 16 + quad * 4 + r;
            const int gy = py0 + (px >> 3), gx = px0 + (px & 7);
            const float gi = acc[mt][0][r];
            const float gf = acc[mt][1][r];
            const float gc = acc[mt][2][r];
            const float go = acc[mt][3][r];
            const float co = mt ? c1[r] : c0[r];
            const float cn = hsig(gf) * co + hsig(gi) * fast_tanh(gc);
            const float hv = hsig(go) * fast_tanh(cn);
            if (mt) cn1[r] = cn; else cn0[r] = cn;
            const size_t pix = ((size_t)(gy * 64 + gx)) * 32 + f;
            hq[pix] = (_Float16)hv;
            oq[pix] = hv * inv + bnb;
        }
    }
    *(f32x4*)cp       = cn0;
    *(f32x4*)(cp + 4) = cn1;
}

extern "C" void kernel_launch(void* const* d_in, const int* in_sizes, int n_in,
                              void* d_out, int out_size, void* d_ws, size_t ws_size,
                              hipStream_t stream)
{
    const float* x      = (const float*)d_in[0];
    const float* Wx     = (const float*)d_in[1];
    const float* Wh     = (const float*)d_in[2];
    const float* bias   = (const float*)d_in[3];
    const float* gamma_ = (const float*)d_in[4];
    const float* beta_  = (const float*)d_in[5];
    const float* mmean  = (const float*)d_in[6];
    const float* mvar   = (const float*)d_in[7];
    float* out = (float*)d_out;

    // ws: [h0 2MB][h1 2MB][csw 4MB][Wcx 72KB][Wch 72KB]
    char* wsb = (char*)d_ws;
    _Float16* h0  = (_Float16*)(wsb);
    _Float16* h1  = (_Float16*)(wsb + (1 << 21));
    float*    csw = (float*)(wsb + (1 << 22));
    _Float16* Wcx = (_Float16*)(wsb + (1 << 23));
    _Float16* Wch = (_Float16*)(wsb + (1 << 23) + 73728);

    prep_w<<<dim3(576), dim3(128), 0, stream>>>(Wx, Wh, Wcx, Wch);

    // 16 fused-step launches. No memset: t=0 skips h-conv and starts c=0 in registers.
    _Float16* hpr = h0;
    _Float16* hnx = h1;
    for (int t = 0; t < 16; ++t) {
        lstm_step_k<<<dim3(8, 8, 8), 256, 0, stream>>>(
            x, Wcx, Wch, bias, gamma_, beta_, mmean, mvar, hpr, hnx, csw, out, t);
        _Float16* tmp = hpr; hpr = hnx; hnx = tmp;
    }
}